// Round 5
// baseline (4073.815 us; speedup 1.0000x reference)
//
#include <hip/hip_runtime.h>
#include <hip/hip_cooperative_groups.h>

namespace cg = cooperative_groups;

#define B_    4
#define S_    512
#define D_    64
#define DFF_  256
#define N_    2048          // B_*S_
#define GWG   256           // 1 block per CU (cooperative-safe)
#define TPB   1024          // 16 waves/block = 4 waves/SIMD
#define RPW   8             // rows per workgroup
#define NSTEPS 4
#define DTs   0.25f

__constant__ float A_tab[6][5] = {
    {0.f, 0.f, 0.f, 0.f, 0.f},
    {0.25f, 0.f, 0.f, 0.f, 0.f},
    {3.0f/32.0f, 9.0f/32.0f, 0.f, 0.f, 0.f},
    {1932.0f/2197.0f, -7200.0f/2197.0f, 7296.0f/2197.0f, 0.f, 0.f},
    {439.0f/216.0f, -8.0f, 3680.0f/513.0f, -845.0f/4104.0f, 0.f},
    {-8.0f/27.0f, 2.0f, -3544.0f/2565.0f, 1859.0f/4104.0f, -11.0f/40.0f}};
__constant__ float B_tab[6] = {16.0f/135.0f, 0.0f, 6656.0f/12825.0f,
                               28561.0f/56430.0f, -9.0f/50.0f, 2.0f/55.0f};

__global__ __launch_bounds__(TPB, 4) void ode_enc_kernel(
    const float* __restrict__ x,
    const float* __restrict__ Wq, const float* __restrict__ bq,
    const float* __restrict__ Wk, const float* __restrict__ bk,
    const float* __restrict__ Wv, const float* __restrict__ bv,
    const float* __restrict__ Wo, const float* __restrict__ bo,
    const float* __restrict__ W1, const float* __restrict__ b1,
    const float* __restrict__ W2, const float* __restrict__ b2,
    float* __restrict__ out,
    float* __restrict__ g_k,    // [2][N_*D_] ping-pong K
    float* __restrict__ g_v,    // [2][N_*D_] ping-pong V
    int*   __restrict__ g_bar)  // [4][24][2] (cnt,flag) — memset 0 per launch
{
    const int wg   = blockIdx.x;
    const int tid  = threadIdx.x;
    const int lane = tid & 63;
    const int wv   = tid >> 6;            // wave id 0..15
    // XCD-aware swizzle: each XCD's 32 blocks serve one half-batch chunk;
    // batch b lives on XCDs {2b, 2b+1}.
    const int sid   = (wg & 7) * 32 + (wg >> 3);
    const int row0  = sid * RPW;
    const int bidx  = sid >> 6;           // batch 0..3
    const int krow0 = bidx * S_;

    const int r_own = wv & 7;             // for tid<512: owned (row, col)
    const int c_own = lane;

    __shared__ float sy[RPW][D_];         // stage input
    __shared__ float sqs[RPW][D_];        // Q projection
    __shared__ float satt[RPW][D_];       // merged attention output
    __shared__ float sh[RPW][D_];         // FFN input
    __shared__ float st[RPW][DFF_];       // relu(h@W1+b1)
    __shared__ float kst[5][RPW][D_];     // RK slopes (same-thread access)
    __shared__ float U[8192];             // partials union (32 KB)

    float ys_reg = 0.f;
    if (tid < 512) ys_reg = x[(row0 + r_own) * D_ + c_own];
    const float bq_r = bq[c_own], bk_r = bk[c_own], bv_r = bv[c_own];
    const float bo_r = bo[c_own], b2_r = b2[c_own];
    const float b1_r = b1[tid & 255];

    for (int step = 0; step < NSTEPS; ++step) {
        for (int stage = 0; stage < 6; ++stage) {
            const int t   = step * 6 + stage;
            const int buf = t & 1;

            // ---------- P1: RK stage input (threads 0..511) ----------
            if (tid < 512) {
                float stin = ys_reg;
                #pragma unroll
                for (int j = 0; j < 5; ++j)
                    if (j < stage) stin = fmaf(DTs * A_tab[stage][j], kst[j][r_own][c_own], stin);
                sy[r_own][c_own] = stin;
            }
            __syncthreads();   // SYNC_A (also orders U reuse from prev stage)

            // ---------- QKV compute: waves 0..11 = (mat, d-quarter) ----------
            if (wv < 12) {
                const int mat = wv >> 2, p = wv & 3;
                const float* Wm = (mat == 0) ? Wq : (mat == 1) ? Wk : Wv;
                float acc[8];
                #pragma unroll
                for (int r = 0; r < 8; ++r) acc[r] = 0.f;
                #pragma unroll
                for (int i4 = 0; i4 < 4; ++i4) {
                    const int dd0 = p * 16 + i4 * 4;
                    const float w0 = Wm[(dd0 + 0) * D_ + lane];
                    const float w1 = Wm[(dd0 + 1) * D_ + lane];
                    const float w2 = Wm[(dd0 + 2) * D_ + lane];
                    const float w3 = Wm[(dd0 + 3) * D_ + lane];
                    #pragma unroll
                    for (int r = 0; r < 8; ++r) {
                        const float4 s4 = *(const float4*)&sy[r][dd0];
                        acc[r] = fmaf(s4.x, w0, fmaf(s4.y, w1, fmaf(s4.z, w2, fmaf(s4.w, w3, acc[r]))));
                    }
                }
                #pragma unroll
                for (int r = 0; r < 8; ++r) U[(wv * 8 + r) * 64 + lane] = acc[r];
            }
            __syncthreads();   // SYNC_B

            // ---------- QKV combine (threads 0..511) ----------
            if (tid < 512) {
                float qa = bq_r, ka = bk_r, va = bv_r;
                #pragma unroll
                for (int p = 0; p < 4; ++p) {
                    qa += U[((0 + p) * 8 + r_own) * 64 + c_own];
                    ka += U[((4 + p) * 8 + r_own) * 64 + c_own];
                    va += U[((8 + p) * 8 + r_own) * 64 + c_own];
                }
                sqs[r_own][c_own] = qa;
                const size_t kidx = ((size_t)buf * N_ + row0 + r_own) * D_ + c_own;
                g_k[kidx] = ka;
                g_v[kidx] = va;
            }

            // ---------- per-batch barrier (64 blocks) ----------
            __threadfence();
            __syncthreads();
            if (tid == 0) {
                int* cnt = g_bar + (bidx * 24 + t) * 2;
                int* flg = cnt + 1;
                const int arr = atomicAdd(cnt, 1);
                if (arr == 63) {
                    atomicExch(flg, 1);
                } else {
                    while (atomicAdd(flg, 0) == 0) __builtin_amdgcn_s_sleep(16);
                }
            }
            __syncthreads();
            __threadfence();

            // ---------- attention: 2 waves per q-row, direct L2 reads ----------
            {
                const int arow = wv >> 1;      // q-row 0..7
                const int half = wv & 1;       // key half (256 keys each)
                const int h  = lane & 7;
                const int ks = lane >> 3;      // 32-key slice within half
                const float SC = 0.51006702f;  // log2(e)/sqrt(8)
                float qv[8];
                #pragma unroll
                for (int d = 0; d < 8; ++d) qv[d] = sqs[arow][h * 8 + d] * SC;

                const float* kb = g_k + ((size_t)buf * N_ + krow0 + half * 256 + ks * 32) * D_ + h * 8;
                const float* vb = g_v + ((size_t)buf * N_ + krow0 + half * 256 + ks * 32) * D_ + h * 8;

                float m = -1e30f, l = 0.f;
                float acc8[8];
                #pragma unroll
                for (int d = 0; d < 8; ++d) acc8[d] = 0.f;

                for (int j0 = 0; j0 < 32; j0 += 4) {
                    float4 kd[4][2], vd[4][2];
                    #pragma unroll
                    for (int u = 0; u < 4; ++u) {
                        const float* kr = kb + (size_t)(j0 + u) * D_;
                        kd[u][0] = *(const float4*)kr;
                        kd[u][1] = *(const float4*)(kr + 4);
                    }
                    #pragma unroll
                    for (int u = 0; u < 4; ++u) {
                        const float* vr = vb + (size_t)(j0 + u) * D_;
                        vd[u][0] = *(const float4*)vr;
                        vd[u][1] = *(const float4*)(vr + 4);
                    }
                    #pragma unroll
                    for (int u = 0; u < 4; ++u) {
                        const float4 ka = kd[u][0], kb2 = kd[u][1];
                        float s = fmaf(qv[0],ka.x,fmaf(qv[1],ka.y,fmaf(qv[2],ka.z,fmaf(qv[3],ka.w,
                                  fmaf(qv[4],kb2.x,fmaf(qv[5],kb2.y,fmaf(qv[6],kb2.z,qv[7]*kb2.w)))))));
                        if (s > m + 8.f) {      // deferred-rescale (T13)
                            const float al = exp2f(m - s);
                            m = s; l *= al;
                            #pragma unroll
                            for (int d = 0; d < 8; ++d) acc8[d] *= al;
                        }
                        const float p = exp2f(s - m);
                        l += p;
                        const float4 va = vd[u][0], vb2 = vd[u][1];
                        acc8[0] = fmaf(p, va.x,  acc8[0]);
                        acc8[1] = fmaf(p, va.y,  acc8[1]);
                        acc8[2] = fmaf(p, va.z,  acc8[2]);
                        acc8[3] = fmaf(p, va.w,  acc8[3]);
                        acc8[4] = fmaf(p, vb2.x, acc8[4]);
                        acc8[5] = fmaf(p, vb2.y, acc8[5]);
                        acc8[6] = fmaf(p, vb2.z, acc8[6]);
                        acc8[7] = fmaf(p, vb2.w, acc8[7]);
                    }
                }

                // merge the 8 ks-slices within the wave (lane bits 3..5)
                #pragma unroll
                for (int off = 8; off < 64; off <<= 1) {
                    const float mo = __shfl_xor(m, off);
                    const float lo = __shfl_xor(l, off);
                    float ab[8];
                    #pragma unroll
                    for (int d = 0; d < 8; ++d) ab[d] = __shfl_xor(acc8[d], off);
                    const float M  = fmaxf(m, mo);
                    const float w1m = exp2f(m - M);
                    const float w2m = exp2f(mo - M);
                    l = l * w1m + lo * w2m;
                    #pragma unroll
                    for (int d = 0; d < 8; ++d) acc8[d] = acc8[d] * w1m + ab[d] * w2m;
                    m = M;
                }
                // raw (unnormalized) partial out + (m,l) to LDS
                if (ks == 0) {
                    const int mi = ((half * 8 + arow) * 8 + h) * 2;
                    U[1024 + mi]     = m;
                    U[1024 + mi + 1] = l;
                }
                float vsel = acc8[0];
                #pragma unroll
                for (int d = 1; d < 8; ++d) vsel = (ks == d) ? acc8[d] : vsel;
                U[(half * 8 + arow) * 64 + h * 8 + ks] = vsel;
            }
            __syncthreads();   // SYNC_C1

            // ---------- merge the two key-halves (threads 0..511) ----------
            if (tid < 512) {
                const int h = c_own >> 3;
                const int m0i = ((0 * 8 + r_own) * 8 + h) * 2;
                const int m1i = ((1 * 8 + r_own) * 8 + h) * 2;
                const float m0 = U[1024 + m0i], l0 = U[1024 + m0i + 1];
                const float m1 = U[1024 + m1i], l1 = U[1024 + m1i + 1];
                const float M  = fmaxf(m0, m1);
                const float w0 = exp2f(m0 - M), w1 = exp2f(m1 - M);
                const float p0 = U[(0 * 8 + r_own) * 64 + c_own];
                const float p1 = U[(1 * 8 + r_own) * 64 + c_own];
                satt[r_own][c_own] = (p0 * w0 + p1 * w1) *
                                     __builtin_amdgcn_rcpf(l0 * w0 + l1 * w1);
            }
            __syncthreads();   // SYNC_C2

            // ---------- Wo compute: wave wv = 4-row d-slice ----------
            {
                const int dd0 = wv * 4;
                const float w0 = Wo[(dd0 + 0) * D_ + lane];
                const float w1 = Wo[(dd0 + 1) * D_ + lane];
                const float w2 = Wo[(dd0 + 2) * D_ + lane];
                const float w3 = Wo[(dd0 + 3) * D_ + lane];
                float acc[8];
                #pragma unroll
                for (int r = 0; r < 8; ++r) {
                    const float4 s4 = *(const float4*)&satt[r][dd0];
                    acc[r] = fmaf(s4.x, w0, fmaf(s4.y, w1, fmaf(s4.z, w2, s4.w * w3)));
                }
                #pragma unroll
                for (int r = 0; r < 8; ++r) U[(wv * 8 + r) * 64 + lane] = acc[r];
            }
            __syncthreads();   // SYNC_D

            // ---------- Wo combine (threads 0..511) ----------
            float so_reg = 0.f;
            if (tid < 512) {
                float a = bo_r;
                #pragma unroll
                for (int w = 0; w < 16; ++w) a += U[(w * 8 + r_own) * 64 + c_own];
                so_reg = a;
                sh[r_own][c_own] = sy[r_own][c_own] + a;
            }
            __syncthreads();   // SYNC_E

            // ---------- FFN1 compute: thread = (c2, d-quarter) ----------
            {
                const int c2 = tid & 255, p = tid >> 8;
                float acc[8];
                #pragma unroll
                for (int r = 0; r < 8; ++r) acc[r] = 0.f;
                #pragma unroll
                for (int i4 = 0; i4 < 4; ++i4) {
                    const int dd0 = p * 16 + i4 * 4;
                    const float w0 = W1[(dd0 + 0) * DFF_ + c2];
                    const float w1 = W1[(dd0 + 1) * DFF_ + c2];
                    const float w2 = W1[(dd0 + 2) * DFF_ + c2];
                    const float w3 = W1[(dd0 + 3) * DFF_ + c2];
                    #pragma unroll
                    for (int r = 0; r < 8; ++r) {
                        const float4 s4 = *(const float4*)&sh[r][dd0];
                        acc[r] = fmaf(s4.x, w0, fmaf(s4.y, w1, fmaf(s4.z, w2, fmaf(s4.w, w3, acc[r]))));
                    }
                }
                #pragma unroll
                for (int r = 0; r < 8; ++r) U[(p * 8 + r) * 256 + c2] = acc[r];
            }
            __syncthreads();   // SYNC_F

            // ---------- FFN1 combine: thread = (c2, row-pair) ----------
            {
                const int c2 = tid & 255, rb = (tid >> 8) * 2;
                #pragma unroll
                for (int i = 0; i < 2; ++i) {
                    const int r = rb + i;
                    st[r][c2] = fmaxf(U[(0 * 8 + r) * 256 + c2] + U[(1 * 8 + r) * 256 + c2] +
                                      U[(2 * 8 + r) * 256 + c2] + U[(3 * 8 + r) * 256 + c2] +
                                      b1_r, 0.f);
                }
            }
            __syncthreads();   // SYNC_G

            // ---------- FFN2 compute: wave wv = 16-wide c2-slice ----------
            {
                float acc[8];
                #pragma unroll
                for (int r = 0; r < 8; ++r) acc[r] = 0.f;
                #pragma unroll
                for (int i4 = 0; i4 < 4; ++i4) {
                    const int cc0 = wv * 16 + i4 * 4;
                    const float w0 = W2[(cc0 + 0) * D_ + lane];
                    const float w1 = W2[(cc0 + 1) * D_ + lane];
                    const float w2 = W2[(cc0 + 2) * D_ + lane];
                    const float w3 = W2[(cc0 + 3) * D_ + lane];
                    #pragma unroll
                    for (int r = 0; r < 8; ++r) {
                        const float4 s4 = *(const float4*)&st[r][cc0];
                        acc[r] = fmaf(s4.x, w0, fmaf(s4.y, w1, fmaf(s4.z, w2, fmaf(s4.w, w3, acc[r]))));
                    }
                }
                #pragma unroll
                for (int r = 0; r < 8; ++r) U[(wv * 8 + r) * 64 + lane] = acc[r];
            }
            __syncthreads();   // SYNC_H

            // ---------- FFN2 combine + k_i / y-update (threads 0..511) ----------
            if (tid < 512) {
                float f = b2_r;
                #pragma unroll
                for (int w = 0; w < 16; ++w) f += U[(w * 8 + r_own) * 64 + c_own];
                const float kv = so_reg + f;
                if (stage < 5) {
                    kst[stage][r_own][c_own] = kv;
                } else {
                    float yn = B_tab[0] * kst[0][r_own][c_own];
                    yn = fmaf(B_tab[2], kst[2][r_own][c_own], yn);
                    yn = fmaf(B_tab[3], kst[3][r_own][c_own], yn);
                    yn = fmaf(B_tab[4], kst[4][r_own][c_own], yn);
                    yn = fmaf(B_tab[5], kv, yn);
                    yn = fmaf(DTs, yn, ys_reg);
                    if (step < NSTEPS - 1) ys_reg = yn;
                    else out[(row0 + r_own) * D_ + c_own] = yn;
                }
            }
            // SYNC_A of the next stage orders U reuse (all waves must pass it
            // before any QKV partial write; waves 0..7 arrive post-combine).
        }
    }
}

extern "C" void kernel_launch(void* const* d_in, const int* in_sizes, int n_in,
                              void* d_out, int out_size, void* d_ws, size_t ws_size,
                              hipStream_t stream) {
    const float* x  = (const float*)d_in[0];
    // d_in[1] = mask: broadcasts over the key axis -> softmax-invariant -> no-op.
    const float* Wq = (const float*)d_in[2];
    const float* bq = (const float*)d_in[3];
    const float* Wk = (const float*)d_in[4];
    const float* bk = (const float*)d_in[5];
    const float* Wv = (const float*)d_in[6];
    const float* bv = (const float*)d_in[7];
    const float* Wo = (const float*)d_in[8];
    const float* bo = (const float*)d_in[9];
    const float* W1 = (const float*)d_in[10];
    const float* b1 = (const float*)d_in[11];
    const float* W2 = (const float*)d_in[12];
    const float* b2 = (const float*)d_in[13];
    float* out  = (float*)d_out;

    float* base = (float*)d_ws;
    float* g_k  = base;                    // 2*N_*D_ floats
    float* g_v  = g_k + 2 * N_ * D_;       // 2*N_*D_ floats
    int*   g_bar = (int*)(g_v + 2 * N_ * D_); // 4*24*2 ints

    // reset barrier state every call (graph-capture legal, deterministic)
    hipMemsetAsync((void*)g_bar, 0, 4 * 24 * 2 * sizeof(int), stream);

    void* args[] = {
        (void*)&x,
        (void*)&Wq, (void*)&bq, (void*)&Wk, (void*)&bk,
        (void*)&Wv, (void*)&bv, (void*)&Wo, (void*)&bo,
        (void*)&W1, (void*)&b1, (void*)&W2, (void*)&b2,
        (void*)&out,
        (void*)&g_k, (void*)&g_v, (void*)&g_bar,
    };
    hipLaunchCooperativeKernel((void*)ode_enc_kernel, dim3(GWG), dim3(TPB),
                               args, 0, stream);
}

// Round 6
// 1309.532 us; speedup vs baseline: 3.1109x; 3.1109x over previous
//
#include <hip/hip_runtime.h>
#include <hip/hip_cooperative_groups.h>

namespace cg = cooperative_groups;

#define B_    4
#define S_    512
#define D_    64
#define DFF_  256
#define N_    2048          // B_*S_
#define GWG   256           // 1 block per CU (cooperative-safe)
#define TPB   512           // 8 waves/block = 2 waves/SIMD
#define RPW   8             // rows per workgroup
#define NSTEPS 4
#define DTs   0.25f

__constant__ float A_tab[6][5] = {
    {0.f, 0.f, 0.f, 0.f, 0.f},
    {0.25f, 0.f, 0.f, 0.f, 0.f},
    {3.0f/32.0f, 9.0f/32.0f, 0.f, 0.f, 0.f},
    {1932.0f/2197.0f, -7200.0f/2197.0f, 7296.0f/2197.0f, 0.f, 0.f},
    {439.0f/216.0f, -8.0f, 3680.0f/513.0f, -845.0f/4104.0f, 0.f},
    {-8.0f/27.0f, 2.0f, -3544.0f/2565.0f, 1859.0f/4104.0f, -11.0f/40.0f}};
__constant__ float B_tab[6] = {16.0f/135.0f, 0.0f, 6656.0f/12825.0f,
                               28561.0f/56430.0f, -9.0f/50.0f, 2.0f/55.0f};

__global__ __launch_bounds__(TPB, 1) void ode_enc_kernel(
    const float* __restrict__ x,
    const float* __restrict__ Wq, const float* __restrict__ bq,
    const float* __restrict__ Wk, const float* __restrict__ bk,
    const float* __restrict__ Wv, const float* __restrict__ bv,
    const float* __restrict__ Wo, const float* __restrict__ bo,
    const float* __restrict__ W1, const float* __restrict__ b1,
    const float* __restrict__ W2, const float* __restrict__ b2,
    float* __restrict__ out,
    float* __restrict__ g_k,    // [2][N_*D_] ping-pong K
    float* __restrict__ g_v)    // [2][N_*D_] ping-pong V
{
    cg::grid_group grid = cg::this_grid();
    const int wg   = blockIdx.x;
    const int tid  = threadIdx.x;
    const int lane = tid & 63;
    const int wv   = tid >> 6;            // wave id 0..7
    // XCD-aware swizzle: each XCD's 32 blocks serve one contiguous sid chunk
    const int sid  = (wg & 7) * 32 + (wg >> 3);
    const int row0  = sid * RPW;
    const int krow0 = (sid >> 6) * S_;    // batch base (64 sids per batch)

    const int r_own = wv;                 // this thread's (row, col) element
    const int c_own = lane;

    __shared__ float sy[RPW][D_];         // stage input
    __shared__ float sqs[RPW][D_];        // Q projection (all rows, LDS)
    __shared__ float satt[RPW][D_];       // attention output
    __shared__ float sh[RPW][D_];         // FFN input
    __shared__ float st[RPW][DFF_];       // relu(h@W1+b1)
    __shared__ float kst[5][RPW][D_];     // RK slopes (same-thread access only)
    __shared__ float U[5120];             // partials union (20.5 KB)

    float ys_reg = x[(row0 + r_own) * D_ + c_own];
    const float bq_r = bq[c_own], bk_r = bk[c_own], bv_r = bv[c_own];
    const float bo_r = bo[c_own], b2_r = b2[c_own];
    const float b1_r = b1[tid & 255];

    for (int step = 0; step < NSTEPS; ++step) {
        for (int stage = 0; stage < 6; ++stage) {
            const int buf = (step * 6 + stage) & 1;

            // ---------- P1: RK stage input ----------
            float stin = ys_reg;
            #pragma unroll
            for (int j = 0; j < 5; ++j)
                if (j < stage) stin = fmaf(DTs * A_tab[stage][j], kst[j][r_own][c_own], stin);
            sy[r_own][c_own] = stin;
            __syncthreads();   // SYNC_A (also orders U reuse)

            // ---------- QKV compute: waves 0..5 = (mat, d-half) ----------
            if (wv < 6) {
                const int mat = wv >> 1, p = wv & 1;
                const float* Wm = (mat == 0) ? Wq : (mat == 1) ? Wk : Wv;
                float acc[8];
                #pragma unroll
                for (int r = 0; r < 8; ++r) acc[r] = 0.f;
                #pragma unroll
                for (int i4 = 0; i4 < 8; ++i4) {
                    const int dd0 = p * 32 + i4 * 4;
                    const float w0 = Wm[(dd0 + 0) * D_ + lane];
                    const float w1 = Wm[(dd0 + 1) * D_ + lane];
                    const float w2 = Wm[(dd0 + 2) * D_ + lane];
                    const float w3 = Wm[(dd0 + 3) * D_ + lane];
                    #pragma unroll
                    for (int r = 0; r < 8; ++r) {
                        const float4 s4 = *(const float4*)&sy[r][dd0];
                        acc[r] = fmaf(s4.x, w0, fmaf(s4.y, w1, fmaf(s4.z, w2, fmaf(s4.w, w3, acc[r]))));
                    }
                }
                #pragma unroll
                for (int r = 0; r < 8; ++r) U[(wv * 8 + r) * 64 + lane] = acc[r];
            }
            __syncthreads();   // SYNC_B

            // ---------- QKV combine ----------
            {
                const float qv = U[(0 * 8 + r_own) * 64 + c_own] + U[(1 * 8 + r_own) * 64 + c_own] + bq_r;
                const float kv = U[(2 * 8 + r_own) * 64 + c_own] + U[(3 * 8 + r_own) * 64 + c_own] + bk_r;
                const float vv = U[(4 * 8 + r_own) * 64 + c_own] + U[(5 * 8 + r_own) * 64 + c_own] + bv_r;
                sqs[r_own][c_own] = qv;
                const size_t kidx = ((size_t)buf * N_ + row0 + r_own) * D_ + c_own;
                g_k[kidx] = kv;
                g_v[kidx] = vv;
            }
            grid.sync();       // K/V of the whole batch visible (+ block sync)

            // ---------- attention: wave = 64-key slice, lane = (head, q-row) ----------
            // 8 lanes sharing a head read identical K/V addresses -> coalescer
            // broadcast; K+V read exactly once per block per stage (256 KB).
            {
                const int h = lane & 7;        // head
                const int r = lane >> 3;       // q-row
                const float SC = 0.51006702f;  // log2(e)/sqrt(8)
                float qv[8];
                {
                    const float4 qa = *(const float4*)&sqs[r][h * 8];
                    const float4 qb = *(const float4*)&sqs[r][h * 8 + 4];
                    qv[0] = qa.x * SC; qv[1] = qa.y * SC; qv[2] = qa.z * SC; qv[3] = qa.w * SC;
                    qv[4] = qb.x * SC; qv[5] = qb.y * SC; qv[6] = qb.z * SC; qv[7] = qb.w * SC;
                }
                const float* kb = g_k + ((size_t)buf * N_ + krow0 + wv * 64) * D_ + h * 8;
                const float* vb = g_v + ((size_t)buf * N_ + krow0 + wv * 64) * D_ + h * 8;

                float m = -1e30f, l = 0.f;
                float acc8[8];
                #pragma unroll
                for (int d = 0; d < 8; ++d) acc8[d] = 0.f;

                for (int j0 = 0; j0 < 64; j0 += 4) {
                    float4 kA[4], kB[4], vA[4], vB[4];
                    #pragma unroll
                    for (int u = 0; u < 4; ++u) {
                        const float* kr = kb + (size_t)(j0 + u) * D_;
                        kA[u] = *(const float4*)kr;
                        kB[u] = *(const float4*)(kr + 4);
                    }
                    #pragma unroll
                    for (int u = 0; u < 4; ++u) {
                        const float* vr = vb + (size_t)(j0 + u) * D_;
                        vA[u] = *(const float4*)vr;
                        vB[u] = *(const float4*)(vr + 4);
                    }
                    float s0, s1, s2, s3;
                    {
                        s0 = fmaf(qv[0],kA[0].x,fmaf(qv[1],kA[0].y,fmaf(qv[2],kA[0].z,fmaf(qv[3],kA[0].w,
                             fmaf(qv[4],kB[0].x,fmaf(qv[5],kB[0].y,fmaf(qv[6],kB[0].z,qv[7]*kB[0].w)))))));
                        s1 = fmaf(qv[0],kA[1].x,fmaf(qv[1],kA[1].y,fmaf(qv[2],kA[1].z,fmaf(qv[3],kA[1].w,
                             fmaf(qv[4],kB[1].x,fmaf(qv[5],kB[1].y,fmaf(qv[6],kB[1].z,qv[7]*kB[1].w)))))));
                        s2 = fmaf(qv[0],kA[2].x,fmaf(qv[1],kA[2].y,fmaf(qv[2],kA[2].z,fmaf(qv[3],kA[2].w,
                             fmaf(qv[4],kB[2].x,fmaf(qv[5],kB[2].y,fmaf(qv[6],kB[2].z,qv[7]*kB[2].w)))))));
                        s3 = fmaf(qv[0],kA[3].x,fmaf(qv[1],kA[3].y,fmaf(qv[2],kA[3].z,fmaf(qv[3],kA[3].w,
                             fmaf(qv[4],kB[3].x,fmaf(qv[5],kB[3].y,fmaf(qv[6],kB[3].z,qv[7]*kB[3].w)))))));
                    }
                    const float bm = fmaxf(fmaxf(s0, s1), fmaxf(s2, s3));
                    if (bm > m + 8.f) {        // deferred-rescale (T13), per 4-key batch
                        const float al = exp2f(m - bm);
                        m = bm; l *= al;
                        #pragma unroll
                        for (int d = 0; d < 8; ++d) acc8[d] *= al;
                    }
                    const float p0 = exp2f(s0 - m);
                    const float p1 = exp2f(s1 - m);
                    const float p2 = exp2f(s2 - m);
                    const float p3 = exp2f(s3 - m);
                    l += (p0 + p1) + (p2 + p3);
                    acc8[0] = fmaf(p0,vA[0].x,fmaf(p1,vA[1].x,fmaf(p2,vA[2].x,fmaf(p3,vA[3].x,acc8[0]))));
                    acc8[1] = fmaf(p0,vA[0].y,fmaf(p1,vA[1].y,fmaf(p2,vA[2].y,fmaf(p3,vA[3].y,acc8[1]))));
                    acc8[2] = fmaf(p0,vA[0].z,fmaf(p1,vA[1].z,fmaf(p2,vA[2].z,fmaf(p3,vA[3].z,acc8[2]))));
                    acc8[3] = fmaf(p0,vA[0].w,fmaf(p1,vA[1].w,fmaf(p2,vA[2].w,fmaf(p3,vA[3].w,acc8[3]))));
                    acc8[4] = fmaf(p0,vB[0].x,fmaf(p1,vB[1].x,fmaf(p2,vB[2].x,fmaf(p3,vB[3].x,acc8[4]))));
                    acc8[5] = fmaf(p0,vB[0].y,fmaf(p1,vB[1].y,fmaf(p2,vB[2].y,fmaf(p3,vB[3].y,acc8[5]))));
                    acc8[6] = fmaf(p0,vB[0].z,fmaf(p1,vB[1].z,fmaf(p2,vB[2].z,fmaf(p3,vB[3].z,acc8[6]))));
                    acc8[7] = fmaf(p0,vB[0].w,fmaf(p1,vB[1].w,fmaf(p2,vB[2].w,fmaf(p3,vB[3].w,acc8[7]))));
                }
                // write partial (m, l, acc8) for (key-slice wv, row r, head h)
                const int pb = ((wv * 8 + r) * 8 + h) * 10;
                #pragma unroll
                for (int d = 0; d < 8; ++d) U[pb + d] = acc8[d];
                U[pb + 8] = m;
                U[pb + 9] = l;
            }
            __syncthreads();   // SYNC_C1

            // ---------- merge the 8 key-slice partials ----------
            {
                const int h = c_own >> 3, d = c_own & 7;
                float mw[8], lw[8], aw[8];
                float M = -1e30f;
                #pragma unroll
                for (int w = 0; w < 8; ++w) {
                    const int pb = ((w * 8 + r_own) * 8 + h) * 10;
                    aw[w] = U[pb + d];
                    mw[w] = U[pb + 8];
                    lw[w] = U[pb + 9];
                    M = fmaxf(M, mw[w]);
                }
                float L = 0.f, A = 0.f;
                #pragma unroll
                for (int w = 0; w < 8; ++w) {
                    const float wt = exp2f(mw[w] - M);
                    L = fmaf(lw[w], wt, L);
                    A = fmaf(aw[w], wt, A);
                }
                satt[r_own][c_own] = A * __builtin_amdgcn_rcpf(L);
            }
            __syncthreads();   // SYNC_C2

            // ---------- Wo compute: wave wv = d-slice ----------
            {
                float acc[8];
                #pragma unroll
                for (int r = 0; r < 8; ++r) acc[r] = 0.f;
                #pragma unroll
                for (int i4 = 0; i4 < 2; ++i4) {
                    const int dd0 = wv * 8 + i4 * 4;
                    const float w0 = Wo[(dd0 + 0) * D_ + lane];
                    const float w1 = Wo[(dd0 + 1) * D_ + lane];
                    const float w2 = Wo[(dd0 + 2) * D_ + lane];
                    const float w3 = Wo[(dd0 + 3) * D_ + lane];
                    #pragma unroll
                    for (int r = 0; r < 8; ++r) {
                        const float4 s4 = *(const float4*)&satt[r][dd0];
                        acc[r] = fmaf(s4.x, w0, fmaf(s4.y, w1, fmaf(s4.z, w2, fmaf(s4.w, w3, acc[r]))));
                    }
                }
                #pragma unroll
                for (int r = 0; r < 8; ++r) U[(wv * 8 + r) * 64 + lane] = acc[r];
            }
            __syncthreads();   // SYNC_D

            // ---------- Wo combine ----------
            float so_reg;
            {
                float a = 0.f;
                #pragma unroll
                for (int w = 0; w < 8; ++w) a += U[(w * 8 + r_own) * 64 + c_own];
                so_reg = a + bo_r;
                sh[r_own][c_own] = stin + so_reg;
            }
            __syncthreads();   // SYNC_E

            // ---------- FFN1 compute: thread = (c2, d-half) ----------
            {
                const int c2 = tid & 255, p = tid >> 8;
                float acc[8];
                #pragma unroll
                for (int r = 0; r < 8; ++r) acc[r] = 0.f;
                #pragma unroll
                for (int i4 = 0; i4 < 8; ++i4) {
                    const int dd0 = p * 32 + i4 * 4;
                    const float w0 = W1[(dd0 + 0) * DFF_ + c2];
                    const float w1 = W1[(dd0 + 1) * DFF_ + c2];
                    const float w2 = W1[(dd0 + 2) * DFF_ + c2];
                    const float w3 = W1[(dd0 + 3) * DFF_ + c2];
                    #pragma unroll
                    for (int r = 0; r < 8; ++r) {
                        const float4 s4 = *(const float4*)&sh[r][dd0];
                        acc[r] = fmaf(s4.x, w0, fmaf(s4.y, w1, fmaf(s4.z, w2, fmaf(s4.w, w3, acc[r]))));
                    }
                }
                #pragma unroll
                for (int r = 0; r < 8; ++r) U[(p * 8 + r) * 256 + c2] = acc[r];
            }
            __syncthreads();   // SYNC_F

            // ---------- FFN1 combine ----------
            {
                const int c2 = tid & 255, rbase = (tid >> 8) * 4;
                #pragma unroll
                for (int i = 0; i < 4; ++i) {
                    const int r = rbase + i;
                    st[r][c2] = fmaxf(U[r * 256 + c2] + U[(8 + r) * 256 + c2] + b1_r, 0.f);
                }
            }
            __syncthreads();   // SYNC_G

            // ---------- FFN2 compute: wave wv = c2-slice ----------
            {
                float acc[8];
                #pragma unroll
                for (int r = 0; r < 8; ++r) acc[r] = 0.f;
                #pragma unroll
                for (int i4 = 0; i4 < 8; ++i4) {
                    const int cc0 = wv * 32 + i4 * 4;
                    const float w0 = W2[(cc0 + 0) * D_ + lane];
                    const float w1 = W2[(cc0 + 1) * D_ + lane];
                    const float w2 = W2[(cc0 + 2) * D_ + lane];
                    const float w3 = W2[(cc0 + 3) * D_ + lane];
                    #pragma unroll
                    for (int r = 0; r < 8; ++r) {
                        const float4 s4 = *(const float4*)&st[r][cc0];
                        acc[r] = fmaf(s4.x, w0, fmaf(s4.y, w1, fmaf(s4.z, w2, fmaf(s4.w, w3, acc[r]))));
                    }
                }
                #pragma unroll
                for (int r = 0; r < 8; ++r) U[(wv * 8 + r) * 64 + lane] = acc[r];
            }
            __syncthreads();   // SYNC_H

            // ---------- FFN2 combine + k_i / y-update ----------
            {
                float f = 0.f;
                #pragma unroll
                for (int w = 0; w < 8; ++w) f += U[(w * 8 + r_own) * 64 + c_own];
                const float kv = so_reg + f + b2_r;
                if (stage < 5) {
                    kst[stage][r_own][c_own] = kv;
                } else {
                    float yn = B_tab[0] * kst[0][r_own][c_own];
                    yn = fmaf(B_tab[2], kst[2][r_own][c_own], yn);
                    yn = fmaf(B_tab[3], kst[3][r_own][c_own], yn);
                    yn = fmaf(B_tab[4], kst[4][r_own][c_own], yn);
                    yn = fmaf(B_tab[5], kv, yn);
                    yn = fmaf(DTs, yn, ys_reg);
                    if (step < NSTEPS - 1) ys_reg = yn;
                    else out[(row0 + r_own) * D_ + c_own] = yn;
                }
            }
            // next stage's SYNC_A orders U reuse; kst is same-thread.
        }
    }
}

extern "C" void kernel_launch(void* const* d_in, const int* in_sizes, int n_in,
                              void* d_out, int out_size, void* d_ws, size_t ws_size,
                              hipStream_t stream) {
    const float* x  = (const float*)d_in[0];
    // d_in[1] = mask: broadcasts over the key axis -> softmax-invariant -> no-op.
    const float* Wq = (const float*)d_in[2];
    const float* bq = (const float*)d_in[3];
    const float* Wk = (const float*)d_in[4];
    const float* bk = (const float*)d_in[5];
    const float* Wv = (const float*)d_in[6];
    const float* bv = (const float*)d_in[7];
    const float* Wo = (const float*)d_in[8];
    const float* bo = (const float*)d_in[9];
    const float* W1 = (const float*)d_in[10];
    const float* b1 = (const float*)d_in[11];
    const float* W2 = (const float*)d_in[12];
    const float* b2 = (const float*)d_in[13];
    float* out  = (float*)d_out;

    float* base = (float*)d_ws;
    float* g_k  = base;                    // 2*N_*D_
    float* g_v  = g_k + 2 * N_ * D_;       // 2*N_*D_

    void* args[] = {
        (void*)&x,
        (void*)&Wq, (void*)&bq, (void*)&Wk, (void*)&bk,
        (void*)&Wv, (void*)&bv, (void*)&Wo, (void*)&bo,
        (void*)&W1, (void*)&b1, (void*)&W2, (void*)&b2,
        (void*)&out,
        (void*)&g_k, (void*)&g_v,
    };
    hipLaunchCooperativeKernel((void*)ode_enc_kernel, dim3(GWG), dim3(TPB),
                               args, 0, stream);
}